// Round 15
// baseline (676.582 us; speedup 1.0000x reference)
//
#include <hip/hip_runtime.h>
#include <hip/hip_bf16.h>

typedef unsigned short bf16_t;
typedef __bf16 bf16x8 __attribute__((ext_vector_type(8)));
typedef float f32x4 __attribute__((ext_vector_type(4)));

__device__ __forceinline__ unsigned short f2bf(float x){
  union { __hip_bfloat16 h; unsigned short u; } c;
  c.h = __float2bfloat16(x);
  return c.u;
}
__device__ __forceinline__ float bf2f(bf16_t u){
  union { unsigned short u; __hip_bfloat16 h; } c;
  c.u = u;
  return __bfloat162float(c.h);
}

// Fragment-linear layout: 1KB tile = 16 rows x 32 k bf16. Matrix =
// tiles[(row>>4)*KT + (k>>5)]; within tile elem = lane*8 + (k&7) with
// lane = ((k>>3)&3)*16 + (row&15)  == exactly the mfma_16x16x32 A/B frag:
// lane l holds row (l&15), k-group (l>>4). One frag = one coalesced
// global_load_dwordx4 (lane l reads tile*1024 + l*16 bytes).
__device__ __forceinline__ size_t pidxf(int m, int k, int KT){
  const int lane = (((k >> 3) & 3) << 4) | (m & 15);
  return ((size_t)((m >> 4)*KT + (k >> 5)))*512 + lane*8 + (k & 7);
}

// ---------------------------------------------------------------------------
// bf16 MFMA GEMM on fragment-packed operands. 128x128 tile, 4 waves (2x2),
// 64x64 per wave. NO LDS, NO BARRIERS: each wave loads its A/B fragments
// straight to registers (16 coalesced dwordx4 per K=64 step) and runs 32 MFMA,
// double-buffered. R13 showed the LDS pipe was ~50% of GEMM time; this
// removes it. Latency hidden by reg double-buffer + TLP; operand re-reads
// served by XCD-local L2.
// kt0 is an A-ONLY k-slab offset (X right-half selection); B always starts
// at slab bks*KchunkT of its own extent.  (R14 bug: kt0 was applied to B.)
// MAP=0: blockIdx=(col,row,ks) -> id%8=col%8 (colTiles%8==0)
// MAP=1: blockIdx=(ks,col,row) -> id%8=ks   (split-K XCD streams)
// ACT: 0 = f32 partial store at ks*csplit; 4 = bf16 store with bias.
// KchunkT = K-chunk in 32-slabs (even, >= 4).
// ---------------------------------------------------------------------------
template<int ACT, int MAP>
__global__ __launch_bounds__(256, 2)
void gemm_frag(const bf16_t* __restrict__ Apk, int KTA, int kt0,
               const bf16_t* __restrict__ Bpk, int KTB,
               float* __restrict__ C, int ldc, size_t csplit,
               const float* __restrict__ bias,
               int M, int KchunkT)
{
  const int tid = threadIdx.x;
  const int w = tid >> 6, lane = tid & 63;
  const int wm = w >> 1, wn = w & 1;
  const int lr = lane & 15, kq = lane >> 4;
  int bcol, brow, bks;
  if (MAP == 0) { bcol = blockIdx.x; brow = blockIdx.y; bks = blockIdx.z; }
  else          { bks = blockIdx.x;  bcol = blockIdx.y; brow = blockIdx.z; }
  const int ksA = kt0 + bks*KchunkT;          // A starting 32-slab
  const int ksB = bks*KchunkT;                // B starting 32-slab
  const int nt = KchunkT >> 1;                // K=64 steps

  const bf16_t* pa[4];
  const bf16_t* pb[4];
#pragma unroll
  for (int q = 0; q < 4; q++) {
    pa[q] = Apk + ((size_t)(brow*8 + wm*4 + q)*KTA + ksA)*512 + lane*8;
    pb[q] = Bpk + ((size_t)(bcol*8 + wn*4 + q)*KTB + ksB)*512 + lane*8;
  }

  bf16x8 a[2][8], b[2][8];                    // [buf][ks*4+q]
  f32x4 acc[4][4] = {};

#define LDT(BUF, T) do { \
    _Pragma("unroll") \
    for (int q = 0; q < 4; q++) { \
      a[BUF][q]     = *(const bf16x8*)(pa[q] + (size_t)(T)*1024); \
      a[BUF][q + 4] = *(const bf16x8*)(pa[q] + (size_t)(T)*1024 + 512); \
      b[BUF][q]     = *(const bf16x8*)(pb[q] + (size_t)(T)*1024); \
      b[BUF][q + 4] = *(const bf16x8*)(pb[q] + (size_t)(T)*1024 + 512); \
    } } while(0)
#define MM(BUF) do { \
    __builtin_amdgcn_s_setprio(1); \
    _Pragma("unroll") \
    for (int ks = 0; ks < 2; ks++) \
      _Pragma("unroll") \
      for (int mi = 0; mi < 4; mi++) \
        _Pragma("unroll") \
        for (int ni = 0; ni < 4; ni++) \
          acc[mi][ni] = __builtin_amdgcn_mfma_f32_16x16x32_bf16( \
              a[BUF][ks*4 + mi], b[BUF][ks*4 + ni], acc[mi][ni], 0, 0, 0); \
    __builtin_amdgcn_s_setprio(0); } while(0)

  LDT(0, 0);
  LDT(1, 1);
  for (int t = 0; t < nt; t += 2) {
    MM(0);
    if (t + 2 < nt) LDT(0, t + 2);
    MM(1);
    if (t + 3 < nt) LDT(1, t + 3);
  }
#undef LDT
#undef MM

  // epilogue: D row = kq*4 + i, col = lane&15 per 16x16 frag
  const int gm0 = brow*128, gn0 = bcol*128;
#pragma unroll
  for (int mi = 0; mi < 4; mi++) {
#pragma unroll
    for (int ni = 0; ni < 4; ni++) {
      const int col = gn0 + wn*64 + ni*16 + lr;
      const float bv = (ACT == 4) ? bias[col] : 0.f;
#pragma unroll
      for (int i = 0; i < 4; i++) {
        const int row = gm0 + wm*64 + mi*16 + kq*4 + i;
        if (row < M) {
          const float v = acc[mi][ni][i] + bv;
          if (ACT == 4) ((bf16_t*)C)[(size_t)row*ldc + col] = f2bf(v);
          else C[(size_t)bks*csplit + (size_t)row*ldc + col] = v;
        }
      }
    }
  }
}

// pack A (pose f32 row-major [M][srcldK]) -> fragment tiles, rows clamped.
__global__ void pack_afrag(const float* __restrict__ src, bf16_t* __restrict__ dst,
                           int M, int srcldK, int KT)
{
  const int bx = blockIdx.x, kt = blockIdx.y;
  __shared__ float s[128][33];
  for (int i = threadIdx.x; i < 1024; i += 256) {
    const int row = i >> 3, kc = (i & 7)*4;
    const int gm = min(bx*128 + row, M-1);
    const float4 v = *(const float4*)(src + (size_t)gm*srcldK + kt*32 + kc);
    s[row][kc] = v.x; s[row][kc+1] = v.y; s[row][kc+2] = v.z; s[row][kc+3] = v.w;
  }
  __syncthreads();
  for (int u = threadIdx.x; u < 512; u += 256) {
    const int t = u >> 6, ln = u & 63;
    const int r = t*16 + (ln & 15), kq = ln >> 4;
    ushort4 v0, v1;
    v0 = make_ushort4(f2bf(s[r][kq*8+0]), f2bf(s[r][kq*8+1]), f2bf(s[r][kq*8+2]), f2bf(s[r][kq*8+3]));
    v1 = make_ushort4(f2bf(s[r][kq*8+4]), f2bf(s[r][kq*8+5]), f2bf(s[r][kq*8+6]), f2bf(s[r][kq*8+7]));
    bf16_t* dt = dst + ((size_t)(bx*8 + t)*KT + kt)*512 + ln*8;
    *(ushort4*)dt = v0;
    *(ushort4*)(dt + 4) = v1;
  }
}

// pack B (f32 [K][srcldN], transposed) -> fragment tiles for n16 groups.
__global__ void pack_bfrag(const float* __restrict__ src, bf16_t* __restrict__ dst,
                           int srcldN, int KT, int n0t, size_t in_batch, int ogb)
{
  const int ntb = blockIdx.x, kt = blockIdx.y, bz = blockIdx.z;
  src += (size_t)bz * in_batch;
  const int ng0 = n0t + bz*ogb + ntb*8;
  __shared__ float s[32][132];
  for (int i = threadIdx.x; i < 4096; i += 256) {
    const int kl = i >> 7, nl = i & 127;
    s[kl][nl] = src[(size_t)(kt*32 + kl)*srcldN + ntb*128 + nl];
  }
  __syncthreads();
  for (int u = threadIdx.x; u < 512; u += 256) {
    const int t = u >> 6, ln = u & 63;
    const int n = t*16 + (ln & 15), kq = ln >> 4;
    ushort4 v0, v1;
    v0 = make_ushort4(f2bf(s[kq*8+0][n]), f2bf(s[kq*8+1][n]), f2bf(s[kq*8+2][n]), f2bf(s[kq*8+3][n]));
    v1 = make_ushort4(f2bf(s[kq*8+4][n]), f2bf(s[kq*8+5][n]), f2bf(s[kq*8+6][n]), f2bf(s[kq*8+7][n]));
    bf16_t* dt = dst + ((size_t)(ng0 + t)*KT + kt)*512 + ln*8;
    *(ushort4*)dt = v0;
    *(ushort4*)(dt + 4) = v1;
  }
}

// sum split-K partials, add bias, write prop f32 + packed X right half
__global__ void reduce_compress(const float* __restrict__ part, const float* __restrict__ bias,
                                float* __restrict__ prop, bf16_t* __restrict__ Xp)
{
  const int idx = blockIdx.x*256 + threadIdx.x;   // < 921600
  const int m = idx >> 10, d = idx & 1023;
  float v = bias[d];
#pragma unroll
  for (int z = 0; z < 8; z++) v += part[(size_t)z*921600 + idx];
  prop[idx] = v;
  Xp[pidxf(m, 1024 + d, 64)] = f2bf(v);
}

// RZ split-2 reduce: v = sigmoid(p0+p1+bias). col<1024: Xh right = bf16(v*prop)
// col>=1024: Zbuf = v.
__global__ void reduce_rz(const float* __restrict__ part, const float* __restrict__ bias,
                          const float* __restrict__ prop, float* __restrict__ Zbuf,
                          bf16_t* __restrict__ Xhp)
{
  const int idx = blockIdx.x*256 + threadIdx.x;   // < 1843200
  const int m = idx >> 11, c = idx & 2047;
  float v = part[idx] + part[1843200 + idx] + bias[c];
  v = 1.f / (1.f + __expf(-v));
  if (c < 1024) Xhp[pidxf(m, 1024 + c, 64)] = f2bf(v * prop[(size_t)m*1024 + c]);
  else          Zbuf[(size_t)m*1024 + (c - 1024)] = v;
}

// h split-4 reduce: h_hat = tanh(sum+bh); prop = (1-z)*prop + z*h_hat
__global__ void reduce_h(const float* __restrict__ part, const float* __restrict__ bias,
                         const float* __restrict__ Zbuf, float* __restrict__ prop,
                         bf16_t* __restrict__ Xp)
{
  const int idx = blockIdx.x*256 + threadIdx.x;   // < 921600
  const int m = idx >> 10, d = idx & 1023;
  float v = bias[d];
#pragma unroll
  for (int z = 0; z < 4; z++) v += part[(size_t)z*921600 + idx];
  v = tanhf(v);
  const float zz = Zbuf[idx];
  const float pn = (1.f - zz)*prop[idx] + zz*v;
  prop[idx] = pn;
  Xp[pidxf(m, 1024 + d, 64)] = f2bf(pn);
}

// u_row[e][h] = sum_d W_edge[e][h][d]*W_att[e][d]; u_col with W_att[e][1024+d]
__global__ void compute_u(const float* __restrict__ We, const float* __restrict__ Wa,
                          float* __restrict__ u_row, float* __restrict__ u_col)
{
  const int w = threadIdx.x >> 6, lane = threadIdx.x & 63;
  const int idx = blockIdx.x*4 + w;               // grid=1792 -> idx<7168
  const int e = idx >> 10, h = idx & 1023;
  const float* wep = We + ((size_t)e*1024 + h)*1024;
  const float* wr  = Wa + (size_t)e*2048;
  const float* wc  = wr + 1024;
  float ar = 0.f, ac = 0.f;
#pragma unroll
  for (int t = 0; t < 16; t++) {
    const float v = wep[lane + 64*t];
    ar += v*wr[lane + 64*t];
    ac += v*wc[lane + 64*t];
  }
  for (int off = 32; off; off >>= 1) { ar += __shfl_down(ar, off); ac += __shfl_down(ac, off); }
  if (lane == 0) { u_row[idx] = ar; u_col[idx] = ac; }
}

// crc[e] = b_edge[e].Wa_row[e], crc[7+e] = b_edge[e].Wa_col[e]
__global__ void crc_kernel(const float* __restrict__ be, const float* __restrict__ Wa,
                           float* __restrict__ crc)
{
  const int w = threadIdx.x >> 6, lane = threadIdx.x & 63;
  for (int idx = w; idx < 14; idx += 4) {
    const int e = idx >> 1, which = idx & 1;
    const float* bp = be + e*1024;
    const float* wp = Wa + (size_t)e*2048 + which*1024;
    float a = 0.f;
#pragma unroll
    for (int t = 0; t < 16; t++) a += bp[lane + 64*t]*wp[lane + 64*t];
    for (int off = 32; off; off >>= 1) a += __shfl_down(a, off);
    if (lane == 0) crc[which*7 + e] = a;
  }
}

// per (b,e): scores
__global__ void attn_kernel(const float* __restrict__ prop, const float* __restrict__ u_row,
                            const float* __restrict__ u_col, const float* __restrict__ crc,
                            const float* __restrict__ b_att, float* __restrict__ scores)
{
  const int b = blockIdx.x, e = blockIdx.y;
  __shared__ float rowv[15], colv[15];
  const int w = threadIdx.x >> 6, lane = threadIdx.x & 63;
  const float* ur = u_row + (size_t)e*1024;
  const float* uc = u_col + (size_t)e*1024;
  for (int n = w; n < 15; n += 4) {
    const float* pr = prop + (size_t)(b*15 + n)*1024;
    float ar = 0.f, ac = 0.f;
#pragma unroll
    for (int t = 0; t < 16; t++) {
      const float pv = pr[lane + 64*t];
      ar += pv*ur[lane + 64*t];
      ac += pv*uc[lane + 64*t];
    }
    for (int off = 32; off; off >>= 1) { ar += __shfl_down(ar, off); ac += __shfl_down(ac, off); }
    if (lane == 0) { rowv[n] = ar; colv[n] = ac; }
  }
  __syncthreads();
  const float base = b_att[e] + crc[e] + crc[7 + e];
  for (int idx = threadIdx.x; idx < 225; idx += 256) {
    const int i = idx/15, j = idx - i*15;
    const float s = 1.f / (1.f + __expf(-(rowv[i] + colv[j] + base)));
    scores[((size_t)(b*7 + e)*15 + i)*15 + j] = s;
  }
}

// merged[b,i,d] = sum_e sum_j scores[b,e,i,j]*msg[b*15+j, e*1024+d]
// -> packed X left AND packed Xh left
__global__ void merged_kernel(const bf16_t* __restrict__ msg, const float* __restrict__ scores,
                              bf16_t* __restrict__ Xp, bf16_t* __restrict__ Xhp)
{
  const int b = blockIdx.x, c = blockIdx.y;   // c: 128-wide d-chunk, 8 chunks
  __shared__ float ms[15*7*128];              // [j][e][dl]
  __shared__ float sc[1575];                  // [e][i][j]
  for (int q = threadIdx.x; q < 3360; q += 256) {
    const int idx = q*4;
    const int j = idx / 896;
    const int rem = idx - j*896;
    const int e = rem >> 7, dl = rem & 127;
    const ushort4 v = *(const ushort4*)(msg + (size_t)(b*15 + j)*7168 + e*1024 + c*128 + dl);
    ms[idx]   = bf2f(v.x);
    ms[idx+1] = bf2f(v.y);
    ms[idx+2] = bf2f(v.z);
    ms[idx+3] = bf2f(v.w);
  }
  for (int idx = threadIdx.x; idx < 1575; idx += 256)
    sc[idx] = scores[(size_t)b*1575 + idx];
  __syncthreads();
  for (int oi = threadIdx.x; oi < 1920; oi += 256) {
    const int i = oi >> 7, dl = oi & 127;
    float acc = 0.f;
#pragma unroll
    for (int e = 0; e < 7; e++)
#pragma unroll
      for (int j = 0; j < 15; j++)
        acc += sc[(e*15 + i)*15 + j] * ms[j*896 + e*128 + dl];
    const bf16_t o = f2bf(acc);
    const int m = b*15 + i, k = c*128 + dl;
    Xp [pidxf(m, k, 64)] = o;
    Xhp[pidxf(m, k, 64)] = o;
  }
}

__global__ void cat2_kernel(const float* __restrict__ a, const float* __restrict__ b,
                            float* __restrict__ o)
{
  const int i = blockIdx.x*256 + threadIdx.x;
  if (i < 1024) o[i] = a[i];
  else if (i < 2048) o[i] = b[i - 1024];
}

// final outputs from last-iteration scores
__global__ void finalize_kernel(const float* __restrict__ scores, float* __restrict__ out)
{
  const int b = blockIdx.x;   // 0..59
  __shared__ float sc[1575];
  __shared__ float act[105];
  __shared__ float asum[15];
  __shared__ float t2[7];
  for (int idx = threadIdx.x; idx < 1575; idx += 256)
    sc[idx] = scores[(size_t)b*1575 + idx];
  __syncthreads();
  for (int idx = threadIdx.x; idx < 105; idx += 256) {
    const int i = idx/7, e = idx - i*7;
    float a = 0.f;
#pragma unroll
    for (int j = 0; j < 15; j++)
      a += (1.f - sc[i*15 + j]) * sc[(e*15 + i)*15 + j];
    act[idx] = a;
    out[(size_t)b*105 + idx] = a;
  }
  for (int idx = threadIdx.x; idx < 225; idx += 256) {
    const int i = idx/15, j = idx - i*15;
    out[6660 + (size_t)b*225 + idx] = 1.f - sc[i*15 + j];
  }
  if (threadIdx.x < 15) {
    const int i = threadIdx.x;
    float s = 0.f;
#pragma unroll
    for (int j = 0; j < 15; j++) s += 1.f - sc[i*15 + j];
    asum[i] = s;
  }
  __syncthreads();
  if (threadIdx.x < 7) {
    const int e = threadIdx.x;
    float t = 0.f;
#pragma unroll
    for (int i = 0; i < 15; i++) t += act[i*7 + e]*asum[i];
    t2[e] = t;
  }
  __syncthreads();
  if (threadIdx.x == 0) {
    float mx = -1e30f;
    for (int e = 1; e < 7; e++) mx = fmaxf(mx, t2[e]);
    float s = 0.f, ex[6];
    for (int e = 1; e < 7; e++) { ex[e-1] = __expf(t2[e] - mx); s += ex[e-1]; }
    for (int e = 1; e < 7; e++) out[6300 + (size_t)b*6 + (e-1)] = ex[e-1]/s;
  }
}

extern "C" void kernel_launch(void* const* d_in, const int* in_sizes, int n_in,
                              void* d_out, int out_size, void* d_ws, size_t ws_size,
                              hipStream_t stream)
{
  const float* pose = (const float*)d_in[0];
  const float* Wc   = (const float*)d_in[1];
  const float* bc   = (const float*)d_in[2];
  const float* We   = (const float*)d_in[3];
  const float* be   = (const float*)d_in[4];
  const float* Wa   = (const float*)d_in[5];
  const float* ba   = (const float*)d_in[6];
  const float* Wr   = (const float*)d_in[7];
  const float* br   = (const float*)d_in[8];
  const float* Wz   = (const float*)d_in[9];
  const float* bz   = (const float*)d_in[10];
  const float* Wh   = (const float*)d_in[11];
  const float* bh   = (const float*)d_in[12];
  float* out = (float*)d_out;

  // ---- workspace carving ----
  char* p = (char*)d_ws;
  auto alloc = [&](size_t b) { char* r = p; p += (b + 255) & ~(size_t)255; return r; };
  bf16_t* Wedgep = (bf16_t*)alloc(448ull*32*1024);   // 14.7 MB [448 ng][32 kt]
  bf16_t* Wrzp   = (bf16_t*)alloc(128ull*64*1024);   //  8.4 MB [128 ng][64 kt]
  bf16_t* Whp    = (bf16_t*)alloc(64ull*64*1024);    //  4.2 MB
  bf16_t* Xp     = (bf16_t*)alloc(64ull*64*1024);    //  4.2 MB [merged|prop]
  float*  prop   = (float*) alloc(900ull*1024*4);    //  3.7 MB f32 state
  float*  scores = (float*) alloc(60ull*1575*4);
  float*  u_row  = (float*) alloc(7168*4);
  float*  u_col  = (float*) alloc(7168*4);
  float*  crc    = (float*) alloc(64);
  float*  brzv   = (float*) alloc(2048*4);
  // phase-union region (136 MB):
  // phase1: Abfp 52.4 @0 | Wcp 52.4 @52.5M | partial 29.5 @105M
  // phase2: msgb 12.9 @0 | Zbuf 3.7 @13M | Xhp 4.2 @17M | partRZ 29.5 @21.5M
  //         | partH 14.7 @51M
  char* r1 = alloc(136000000ull);
  bf16_t* Abfp    = (bf16_t*)r1;                     // [64 mg][800 kt]
  bf16_t* Wcp     = (bf16_t*)(r1 + 52500000ull);     // [64 ng][800 kt]
  float*  partial = (float*) (r1 + 105000000ull);
  bf16_t* msgb    = (bf16_t*)r1;
  float*  Zbuf    = (float*) (r1 + 13000000ull);
  bf16_t* Xhp     = (bf16_t*)(r1 + 17000000ull);
  float*  partRZ  = (float*) (r1 + 21500000ull);     // 2 x 900 x 2048 f32
  float*  partH   = (float*) (r1 + 51000000ull);     // 4 x 900 x 1024 f32

  // ---- precompute: pack everything into fragment layout ----
  compute_u<<<1792, 256, 0, stream>>>(We, Wa, u_row, u_col);
  crc_kernel<<<1, 256, 0, stream>>>(be, Wa, crc);
  cat2_kernel<<<8, 256, 0, stream>>>(br, bz, brzv);
  pack_afrag<<<dim3(8,800), 256, 0, stream>>>(pose, Abfp, 900, 25600, 800);
  pack_bfrag<<<dim3(8,800), 256, 0, stream>>>(Wc, Wcp, 1024, 800, 0, 0, 0);
  pack_bfrag<<<dim3(8,32,7), 256, 0, stream>>>(We, Wedgep, 1024, 32, 0,
                                               1024ull*1024, 64);
  pack_bfrag<<<dim3(8,64), 256, 0, stream>>>(Wr, Wrzp, 1024, 64, 0, 0, 0);
  pack_bfrag<<<dim3(8,64), 256, 0, stream>>>(Wz, Wrzp, 1024, 64, 64, 0, 0);
  pack_bfrag<<<dim3(8,64), 256, 0, stream>>>(Wh, Whp, 1024, 64, 0, 0, 0);

  // compress: prop = pose @ W_compress + b_compress
  // MAP1 (8,8,8): id%8=ks, KchunkT=100 slabs (K=3200), nt=50
  gemm_frag<0,1><<<dim3(8,8,8), 256, 0, stream>>>(Abfp, 800, 0, Wcp, 800,
      partial, 1024, 921600ull, nullptr, 900, 100);
  reduce_compress<<<3600, 256, 0, stream>>>(partial, bc, prop, Xp);

  // ---- 6 recurrent iterations (last one: scores only) ----
  for (int it = 0; it < 6; it++) {
    attn_kernel<<<dim3(60,7), 256, 0, stream>>>(prop, u_row, u_col, crc, ba, scores);
    if (it == 5) break;
    // msg = prop @ W_edge + b_edge  (A = X right half: kt0=32), MAP0 (56,8)
    gemm_frag<4,0><<<dim3(56,8,1), 256, 0, stream>>>(Xp, 64, 32, Wedgep, 32,
        (float*)msgb, 7168, 0, be, 900, 32);
    merged_kernel<<<dim3(60,8), 256, 0, stream>>>(msgb, scores, Xp, Xhp);
    // [r|z] = X @ [Wr|Wz]  (MAP0 (16,8,2): ks=2, KchunkT=32, nt=16)
    gemm_frag<0,0><<<dim3(16,8,2), 256, 0, stream>>>(Xp, 64, 0, Wrzp, 64,
        partRZ, 2048, 1843200ull, nullptr, 900, 32);
    reduce_rz<<<7200, 256, 0, stream>>>(partRZ, brzv, prop, Zbuf, Xhp);
    // h = Xh @ Wh  (MAP0 (8,8,4): ks=4, KchunkT=16, nt=8)
    gemm_frag<0,0><<<dim3(8,8,4), 256, 0, stream>>>(Xhp, 64, 0, Whp, 64,
        partH, 1024, 921600ull, nullptr, 900, 16);
    reduce_h<<<3600, 256, 0, stream>>>(partH, bh, Zbuf, prop, Xp);
  }

  finalize_kernel<<<60, 256, 0, stream>>>(scores, out);
}